// Round 15
// baseline (131.975 us; speedup 1.0000x reference)
//
#include <hip/hip_runtime.h>
#include <math.h>
#include <stdint.h>

#define RB 256      // block size (gt/final)
#define RSB 1024    // block size (rank_scatter)
#define GM 1024     // Gauss-transform grid points
#define YS 128      // source-splits in gt phase

#define SCALE 0.84932180028801904f   // 1/sqrt(2 ln2): exp(-d^2/2) = exp2(-(SCALE*d)^2)
#define SQRT2PI 2.5066282746310002f
#define KFP 0.46971863934f           // 1/(SCALE*sqrt(2pi)) : dPhiSum/dx = KFP*A
#define LN2 0.69314718056f

__device__ __forceinline__ unsigned float2ord(float f) {
  unsigned u = __float_as_uint(f);
  return (u & 0x80000000u) ? ~u : (u | 0x80000000u);
}
__device__ __forceinline__ float ord2float(unsigned u) {
  return __uint_as_float((u & 0x80000000u) ? (u ^ 0x80000000u) : ~u);
}
__device__ __forceinline__ uint64_t order_key(float f, int idx) {
  return ((uint64_t)float2ord(f) << 32) | (unsigned)idx;
}
__device__ __forceinline__ float e_of(const float* theta, const float* dur, int i) {
  return logf(dur[i] + 1e-32f) - theta[i];   // deterministic: identical everywhere
}

// grid geometry from the sorted endpoints (identical fp ops in every consumer)
__device__ __forceinline__ void grid_geom(const float2* xe, int n, float* x0, float* hx) {
  float a = xe[0].x - 7.0f;        // ~8 sigma margin in prescaled units
  float b = xe[n - 1].x + 7.0f;
  *x0 = a;
  *hx = (b - a) / (float)(GM - 1);
}

// ---------------------------------------------------------------------------
// Kernel 1: SELF-CONTAINED counting-rank + scatter (no cross-block deps, no
// atomics). Grid = n/256 blocks x 1024 threads. Each block:
//   - computes ALL n keys inline into 64 KB LDS,
//   - 4 threads per i-element, each counting over one quarter (wave-uniform
//     j -> LDS broadcast reads),
//   - LDS-reduces the 4 partials -> rank[i] (== inverse permutation),
//   - scatters: xe[rank].x = SCALE*e, xe[i].y = ev[rank], th_s[i] = theta[rank].
// Block 0 additionally zeroes gbuf and out.
// ---------------------------------------------------------------------------
__global__ __launch_bounds__(RSB) void rank_scatter_kernel(
    const float* __restrict__ theta, const float* __restrict__ dur,
    const int* __restrict__ ev, float2* __restrict__ xe,
    float* __restrict__ th_s, float* __restrict__ gbuf,
    float* __restrict__ out, int n) {
  __shared__ uint64_t kt[8192];          // 64 KB: all n keys
  __shared__ int part[4][256];           // [quarter][i_local] - conflict-free

  for (int j = threadIdx.x; j < n; j += RSB)
    kt[j] = order_key(e_of(theta, dur, j), j);
  if (blockIdx.x == 0) {                 // absorb zero-init (sequential stream)
    for (int m = threadIdx.x; m < 4 * GM; m += RSB) gbuf[m] = 0.0f;
    if (threadIdx.x == 0) out[0] = 0.0f;
  }
  __syncthreads();

  const int il = threadIdx.x & 255;      // i_local
  const int q  = threadIdx.x >> 8;       // quarter (wave-uniform: 4 waves/q)
  const int i  = blockIdx.x * 256 + il;
  const uint64_t ki = kt[i];
  const int qlen = n >> 2;
  const int jb = q * qlen;
  int cnt = 0;
  #pragma unroll 8
  for (int jj = 0; jj < qlen; ++jj)
    cnt += (kt[jb + jj] < ki) ? 1 : 0;   // broadcast read (uniform in wave)
  part[q][il] = cnt;
  __syncthreads();

  if (q == 0) {
    int r = part[0][il] + part[1][il] + part[2][il] + part[3][il];
    float ei = ord2float((unsigned)(ki >> 32));     // bit-exact e_i from key
    ((float*)&xe[r])[0] = SCALE * ei;    // scatter (distinct dword, no race)
    ((float*)&xe[i])[1] = (float)ev[r];  // reference's inverse-perm reorder
    th_s[i] = theta[r];
  }
}

// ---------------------------------------------------------------------------
// Kernel 2: Gauss transform on the grid. dp = x_m - x_j (prescaled).
//   A = sum g                    (pdf basis; FPhi' = KFP*A)
//   B = sum ev*g                 (condE numerator; B' = -2*ln2*D)
//   F = sum Phi(d)               (cdf-sum via 3-term erf reusing g)
//   D = sum dp*ev*g
// Sources are block-uniform float2 -> one s_load_dwordx2 per source.
// ---------------------------------------------------------------------------
__global__ __launch_bounds__(RB) void gt_kernel(
    const float2* __restrict__ xe, float* __restrict__ gbuf, int n) {
  float x0, hx;
  grid_geom(xe, n, &x0, &hx);
  int m = blockIdx.x * RB + threadIdx.x;        // gridDim.x = GM/RB = 4
  float xm = fmaf((float)m, hx, x0);
  const int chunk = n / YS;                      // 64
  int jb = blockIdx.y * chunk;
  const float P2S = 0.39169197f;   // 0.47047*sqrt(ln2): t = 1/(1+p|d|/sqrt2)
  float a = 0.0f, b = 0.0f, f = 0.0f, d = 0.0f;
  #pragma unroll 8
  for (int jj = 0; jj < chunk; ++jj) {
    float2 q = xe[jb + jj];                      // uniform -> s_load_dwordx2
    float dp = xm - q.x;
    float g = __builtin_amdgcn_exp2f(-(dp * dp));  // exp(-d^2/2)
    float evg = q.y * g;
    a += g;
    b += evg;
    d = fmaf(dp, evg, d);
    // A&S 7.1.25 erf (p=0.47047, |err|<=2.5e-5), reuses g
    float tt = __builtin_amdgcn_rcpf(fmaf(P2S, __builtin_fabsf(dp), 1.0f));
    float poly = tt * (0.3480242f + tt * (-0.0958798f + tt * 0.7478556f));
    f += __builtin_copysignf(fmaf(-poly, g, 1.0f), dp);   // sign*erf
  }
  atomicAdd(&gbuf[m], a);
  atomicAdd(&gbuf[GM + m], b);
  atomicAdd(&gbuf[2 * GM + m], 0.5f * (float)chunk + 0.5f * f);  // Phi = .5+.5*s
  atomicAdd(&gbuf[3 * GM + m], d);
}

// ---------------------------------------------------------------------------
// Kernel 3: per-element cubic Hermite interpolation of FPhi (cdf-sum) and B
// (pdf*ev sum), then the loss terms. One atomic per block into zeroed out.
// ---------------------------------------------------------------------------
__global__ __launch_bounds__(RB) void final_kernel(
    const float2* __restrict__ xe, const float* __restrict__ th_s,
    const float* __restrict__ gbuf, float* __restrict__ out, int n) {
  float x0, hx;
  grid_geom(xe, n, &x0, &hx);
  const float* A = gbuf;
  const float* B = gbuf + GM;
  const float* F = gbuf + 2 * GM;
  const float* D = gbuf + 3 * GM;
  int i = blockIdx.x * RB + threadIdx.x;

  float term = 0.0f;
  if (i < n) {
    float2 q = xe[i];
    float u = (q.x - x0) * __builtin_amdgcn_rcpf(hx);
    int m = (int)u;
    m = min(max(m, 0), GM - 2);
    float t = u - (float)m;
    t = fminf(fmaxf(t, 0.0f), 1.0f);
    float t2 = t * t, t3 = t2 * t;
    float h00 = 2.0f * t3 - 3.0f * t2 + 1.0f;
    float h01 = 3.0f * t2 - 2.0f * t3;
    float h10 = t3 - 2.0f * t2 + t;
    float h11 = t3 - t2;
    float Fi = F[m] * h00 + F[m + 1] * h01 +
               hx * KFP * (A[m] * h10 + A[m + 1] * h11);
    float Bi = B[m] * h00 + B[m + 1] * h01 -
               2.0f * LN2 * hx * (D[m] * h10 + D[m + 1] * h11);
    const float fn = (float)n;
    float condE = fmaxf(Bi, 0.0f) * (1.0f / SQRT2PI) / fn + fn * 1e-32f;
    float surv = fmaxf(Fi, 0.25f) / fn;    // exact math gives Fi >= 0.5
    term = (__logf(condE) - __logf(surv) + th_s[i]) * q.y;
  }

  #pragma unroll
  for (int off = 32; off > 0; off >>= 1) term += __shfl_down(term, off, 64);
  __shared__ float red[RB / 64];
  int wave = threadIdx.x >> 6, lane = threadIdx.x & 63;
  if (lane == 0) red[wave] = term;
  __syncthreads();
  if (threadIdx.x == 0) {
    float s = 0.0f;
    #pragma unroll
    for (int w = 0; w < RB / 64; ++w) s += red[w];
    atomicAdd(out, -s / (float)n);
  }
}

extern "C" void kernel_launch(void* const* d_in, const int* in_sizes, int n_in,
                              void* d_out, int out_size, void* d_ws, size_t ws_size,
                              hipStream_t stream) {
  const float* theta = (const float*)d_in[0];   // log_h (n,1) fp32
  const float* dur   = (const float*)d_in[1];   // durations (n,) fp32
  const int*   ev    = (const int*)d_in[2];     // events (n,) int32
  float* out = (float*)d_out;
  const int n = in_sizes[1];

  // workspace layout (8-byte aligned first)
  char* ws = (char*)d_ws;
  float2* xe   = (float2*)ws;  ws += n * sizeof(float2);
  float*  th_s = (float*)ws;   ws += n * sizeof(float);
  float*  gbuf = (float*)ws;   ws += 4 * GM * sizeof(float);  // A|B|F|D

  rank_scatter_kernel<<<n / 256, RSB, 0, stream>>>(theta, dur, ev, xe, th_s,
                                                   gbuf, out, n);
  gt_kernel<<<dim3(GM / RB, YS), RB, 0, stream>>>(xe, gbuf, n);
  final_kernel<<<n / RB, RB, 0, stream>>>(xe, th_s, gbuf, out, n);
}

// Round 16
// 77.708 us; speedup vs baseline: 1.6984x; 1.6984x over previous
//
#include <hip/hip_runtime.h>
#include <math.h>
#include <stdint.h>

#define RB 256      // block size
#define JT 512      // j-tile (keys) per block in rank phase
#define GM 1024     // Gauss-transform grid points
#define YS 128      // source-splits in gt phase

#define SCALE 0.84932180028801904f   // 1/sqrt(2 ln2): exp(-d^2/2) = exp2(-(SCALE*d)^2)
#define SQRT2PI 2.5066282746310002f
#define KFP 0.46971863934f           // 1/(SCALE*sqrt(2pi)) : dPhiSum/dx = KFP*A
#define LN2 0.69314718056f

__device__ __forceinline__ uint64_t order_key(float f, int idx) {
  unsigned u = __float_as_uint(f);
  u = (u & 0x80000000u) ? ~u : (u | 0x80000000u);
  return ((uint64_t)u << 32) | (unsigned)idx;
}

__device__ __forceinline__ float e_of(const float* theta, const float* dur, int i) {
  return logf(dur[i] + 1e-32f) - theta[i];   // deterministic: identical everywhere
}

// grid geometry from the sorted endpoints (identical fp ops in every consumer)
__device__ __forceinline__ void grid_geom(const float2* xe, int n, float* x0, float* hx) {
  float a = xe[0].x - 7.0f;        // ~8 sigma margin in prescaled units
  float b = xe[n - 1].x + 7.0f;
  *x0 = a;
  *hx = (b - a) / (float)(GM - 1);
}

// ---------------------------------------------------------------------------
// Kernel 1: counting-rank partials. Block (ich, jch) writes
// rank_part[jch*n + i] exactly once (no zero-init, no atomics). Keys computed
// inline from theta/dur (deterministic -> identical in every block).
// ---------------------------------------------------------------------------
__global__ __launch_bounds__(RB) void rank_part_kernel(
    const float* __restrict__ theta, const float* __restrict__ dur,
    int* __restrict__ rank_part, int n) {
  __shared__ uint64_t kt[JT];
  const int i = blockIdx.x * RB + threadIdx.x;
  uint64_t ki = order_key(e_of(theta, dur, i), i);
  const int jbase = blockIdx.y * JT;
  for (int t = threadIdx.x; t < JT; t += RB) {
    int j = jbase + t;
    kt[t] = order_key(e_of(theta, dur, j), j);
  }
  __syncthreads();
  int cnt = 0;
  #pragma unroll 8
  for (int jj = 0; jj < JT; ++jj) cnt += (kt[jj] < ki) ? 1 : 0;   // LDS broadcast
  rank_part[blockIdx.y * n + i] = cnt;
}

// ---------------------------------------------------------------------------
// Kernel 2: sum partials -> rank (== inverse permutation), then scatter into
// the interleaved (x, ev) array:
//   xe[rank[k]].x = SCALE*e[k]   (prescaled e_sorted, scatter - distinct dword)
//   xe[k].y       = ev[rank[k]]  (reference's inverse-perm side reorder)
//   th_s[k]       = theta[rank[k]]
// Also zeroes gbuf (4*GM = 4096 <= n) and out[0].
// ---------------------------------------------------------------------------
__global__ __launch_bounds__(RB) void scatter_kernel(
    const float* __restrict__ theta, const float* __restrict__ dur,
    const int* __restrict__ ev, const int* __restrict__ rank_part,
    float2* __restrict__ xe, float* __restrict__ th_s,
    float* __restrict__ gbuf, float* __restrict__ out, int n) {
  int k = blockIdx.x * RB + threadIdx.x;
  int r = 0;
  const int nj = n / JT;                 // 16
  #pragma unroll 16
  for (int jch = 0; jch < nj; ++jch) r += rank_part[jch * n + k];   // coalesced
  ((float*)&xe[r])[0] = SCALE * e_of(theta, dur, k);
  ((float*)&xe[k])[1] = (float)ev[r];
  th_s[k] = theta[r];
  if (k < 4 * GM) gbuf[k] = 0.0f;
  if (k == 0) out[0] = 0.0f;
}

// ---------------------------------------------------------------------------
// Kernel 3: Gauss transform on the grid. dp = x_m - x_j (prescaled).
//   A = sum g                    (pdf basis; FPhi' = KFP*A)
//   B = sum ev*g                 (condE numerator; B' = -2*ln2*D)
//   F = sum Phi(d)               (cdf-sum via 3-term erf reusing g)
//   D = sum dp*ev*g
// Sources are block-uniform float2 -> one s_load_dwordx2 per source.
// ---------------------------------------------------------------------------
__global__ __launch_bounds__(RB) void gt_kernel(
    const float2* __restrict__ xe, float* __restrict__ gbuf, int n) {
  float x0, hx;
  grid_geom(xe, n, &x0, &hx);
  int m = blockIdx.x * RB + threadIdx.x;        // gridDim.x = GM/RB = 4
  float xm = fmaf((float)m, hx, x0);
  const int chunk = n / YS;                      // 64
  int jb = blockIdx.y * chunk;
  const float P2S = 0.39169197f;   // 0.47047*sqrt(ln2): t = 1/(1+p|d|/sqrt2)
  float a = 0.0f, b = 0.0f, f = 0.0f, d = 0.0f;
  #pragma unroll 8
  for (int jj = 0; jj < chunk; ++jj) {
    float2 q = xe[jb + jj];                      // uniform -> s_load_dwordx2
    float dp = xm - q.x;
    float g = __builtin_amdgcn_exp2f(-(dp * dp));  // exp(-d^2/2)
    float evg = q.y * g;
    a += g;
    b += evg;
    d = fmaf(dp, evg, d);
    // A&S 7.1.25 erf (p=0.47047, |err|<=2.5e-5), reuses g
    float tt = __builtin_amdgcn_rcpf(fmaf(P2S, __builtin_fabsf(dp), 1.0f));
    float poly = tt * (0.3480242f + tt * (-0.0958798f + tt * 0.7478556f));
    f += __builtin_copysignf(fmaf(-poly, g, 1.0f), dp);   // sign*erf
  }
  atomicAdd(&gbuf[m], a);
  atomicAdd(&gbuf[GM + m], b);
  atomicAdd(&gbuf[2 * GM + m], 0.5f * (float)chunk + 0.5f * f);  // Phi = .5+.5*s
  atomicAdd(&gbuf[3 * GM + m], d);
}

// ---------------------------------------------------------------------------
// Kernel 4: per-element cubic Hermite interpolation of FPhi (cdf-sum) and B
// (pdf*ev sum), then the loss terms. One atomic per block into zeroed out.
// ---------------------------------------------------------------------------
__global__ __launch_bounds__(RB) void final_kernel(
    const float2* __restrict__ xe, const float* __restrict__ th_s,
    const float* __restrict__ gbuf, float* __restrict__ out, int n) {
  float x0, hx;
  grid_geom(xe, n, &x0, &hx);
  const float* A = gbuf;
  const float* B = gbuf + GM;
  const float* F = gbuf + 2 * GM;
  const float* D = gbuf + 3 * GM;
  int i = blockIdx.x * RB + threadIdx.x;

  float term = 0.0f;
  if (i < n) {
    float2 q = xe[i];
    float u = (q.x - x0) * __builtin_amdgcn_rcpf(hx);
    int m = (int)u;
    m = min(max(m, 0), GM - 2);
    float t = u - (float)m;
    t = fminf(fmaxf(t, 0.0f), 1.0f);
    float t2 = t * t, t3 = t2 * t;
    float h00 = 2.0f * t3 - 3.0f * t2 + 1.0f;
    float h01 = 3.0f * t2 - 2.0f * t3;
    float h10 = t3 - 2.0f * t2 + t;
    float h11 = t3 - t2;
    float Fi = F[m] * h00 + F[m + 1] * h01 +
               hx * KFP * (A[m] * h10 + A[m + 1] * h11);
    float Bi = B[m] * h00 + B[m + 1] * h01 -
               2.0f * LN2 * hx * (D[m] * h10 + D[m + 1] * h11);
    const float fn = (float)n;
    float condE = fmaxf(Bi, 0.0f) * (1.0f / SQRT2PI) / fn + fn * 1e-32f;
    float surv = fmaxf(Fi, 0.25f) / fn;    // exact math gives Fi >= 0.5
    term = (__logf(condE) - __logf(surv) + th_s[i]) * q.y;
  }

  #pragma unroll
  for (int off = 32; off > 0; off >>= 1) term += __shfl_down(term, off, 64);
  __shared__ float red[RB / 64];
  int wave = threadIdx.x >> 6, lane = threadIdx.x & 63;
  if (lane == 0) red[wave] = term;
  __syncthreads();
  if (threadIdx.x == 0) {
    float s = 0.0f;
    #pragma unroll
    for (int w = 0; w < RB / 64; ++w) s += red[w];
    atomicAdd(out, -s / (float)n);
  }
}

extern "C" void kernel_launch(void* const* d_in, const int* in_sizes, int n_in,
                              void* d_out, int out_size, void* d_ws, size_t ws_size,
                              hipStream_t stream) {
  const float* theta = (const float*)d_in[0];   // log_h (n,1) fp32
  const float* dur   = (const float*)d_in[1];   // durations (n,) fp32
  const int*   ev    = (const int*)d_in[2];     // events (n,) int32
  float* out = (float*)d_out;
  const int n = in_sizes[1];

  // workspace layout (8-byte aligned first)
  char* ws = (char*)d_ws;
  float2* xe        = (float2*)ws;  ws += n * sizeof(float2);
  int*    rank_part = (int*)ws;     ws += (n / JT) * n * sizeof(int);
  float*  th_s      = (float*)ws;   ws += n * sizeof(float);
  float*  gbuf      = (float*)ws;   ws += 4 * GM * sizeof(float);  // A|B|F|D

  rank_part_kernel<<<dim3(n / RB, n / JT), RB, 0, stream>>>(theta, dur, rank_part, n);
  scatter_kernel<<<n / RB, RB, 0, stream>>>(theta, dur, ev, rank_part,
                                            xe, th_s, gbuf, out, n);
  gt_kernel<<<dim3(GM / RB, YS), RB, 0, stream>>>(xe, gbuf, n);
  final_kernel<<<n / RB, RB, 0, stream>>>(xe, th_s, gbuf, out, n);
}